// Round 2
// baseline (93.600 us; speedup 1.0000x reference)
//
#include <hip/hip_runtime.h>

namespace {
constexpr int kB      = 256;
constexpr int kT      = 336;
constexpr int kC      = 512;
constexpr int kK      = 3;
constexpr int kChunks = 4;            // one wave per T-chunk
constexpr int kTc     = kT / kChunks; // 84
constexpr int kCTile  = 64;           // c's per block (one per lane)
}

// Block = (b, 64-wide c-tile). 256 threads = 4 waves; wave j owns T-chunk j
// (84 steps). Two passes over the chunk:
//   pass 1: local weighted-cumsum totals per k  -> LDS
//   (barrier; each thread sums totals of earlier chunks = prefix offset O_k)
//   pass 2: re-scan with S initialized to O_k, emit y = sum_k S*mixw*inv.
// Weights: w[t] = a^t*(1-a) (w[0]=1); inv[t] = min(a^-t, 1e8) == 1/max(a^t,1e-8).
// Chunk-start coefficients via powf(a, 84j). x is read twice; second read is
// L1/L2-resident (21.5 KB per wave, temporally adjacent).
__global__ __launch_bounds__(256) void ema_mix_kernel(
    const float* __restrict__ x,
    const float* __restrict__ logit_alpha,
    const float* __restrict__ mix_logits,
    float* __restrict__ out)
{
    __shared__ float s_tot[kK][kChunks][kCTile];  // [k][chunk][ci] -> lane-consecutive, conflict-free

    const int tid = threadIdx.x;
    const int ci  = tid & (kCTile - 1);
    const int j   = tid >> 6;                // chunk / wave index 0..3
    const int c0  = (blockIdx.x & 7) << 6;   // 8 c-tiles
    const int b   = blockIdx.x >> 3;
    const int c   = c0 + ci;

    // ---- per-(k,c) parameters ----
    float a[kK], oma[kK], inva[kK], mixw[kK];
    {
        float logits[kK];
        float lmax = -3.402823e38f;
        #pragma unroll
        for (int k = 0; k < kK; ++k) {
            logits[k] = mix_logits[c * kK + k];
            lmax = fmaxf(lmax, logits[k]);
        }
        float esum = 0.f;
        #pragma unroll
        for (int k = 0; k < kK; ++k) {
            logits[k] = expf(logits[k] - lmax);
            esum += logits[k];
        }
        const float rs = 1.0f / esum;
        #pragma unroll
        for (int k = 0; k < kK; ++k) {
            mixw[k] = logits[k] * rs;
            const float z = logit_alpha[k * kC + c];
            float s;
            if (z >= 0.f) {
                s = 1.0f / (1.0f + expf(-z));
            } else {
                const float e = expf(z);
                s = e / (1.0f + e);
            }
            s = fminf(fmaxf(s, 1e-4f), (float)(1.0 - 1e-4));
            a[k]    = s;
            oma[k]  = 1.0f - s;
            inva[k] = 1.0f / s;
        }
    }

    const int t0 = j * kTc;
    float ap0[kK], vi0[kK];
    #pragma unroll
    for (int k = 0; k < kK; ++k) {
        ap0[k] = powf(a[k], (float)t0);   // a^(84j); j=0 -> exactly 1
        vi0[k] = 1.0f / ap0[k];           // a^(-84j); overflow->inf is fine (clamped)
    }

    const float* xp = x   + ((size_t)b * kT + t0) * kC + c;
    float*       op = out + ((size_t)b * kT + t0) * kC + c;

    // ---- pass 1: chunk totals ----
    float Tk[kK] = {0.f, 0.f, 0.f};
    {
        float ap[kK];
        #pragma unroll
        for (int k = 0; k < kK; ++k) ap[k] = ap0[k];
        #pragma unroll 4
        for (int i = 0; i < kTc; ++i) {
            const float xv = xp[(size_t)i * kC];
            const int t = t0 + i;
            #pragma unroll
            for (int k = 0; k < kK; ++k) {
                const float w = (t == 0) ? 1.0f : ap[k] * oma[k];
                Tk[k] = fmaf(xv, w, Tk[k]);
                ap[k] *= a[k];
            }
        }
    }
    #pragma unroll
    for (int k = 0; k < kK; ++k) s_tot[k][j][ci] = Tk[k];
    __syncthreads();

    float O[kK] = {0.f, 0.f, 0.f};
    #pragma unroll
    for (int k = 0; k < kK; ++k) {
        #pragma unroll
        for (int jj = 0; jj < kChunks - 1; ++jj) {
            if (jj < j) O[k] += s_tot[k][jj][ci];
        }
    }

    // ---- pass 2: scan with prefix offset, emit output ----
    {
        float ap[kK], vi[kK], S[kK];
        #pragma unroll
        for (int k = 0; k < kK; ++k) { ap[k] = ap0[k]; vi[k] = vi0[k]; S[k] = O[k]; }
        #pragma unroll 4
        for (int i = 0; i < kTc; ++i) {
            const float xv = xp[(size_t)i * kC];
            const int t = t0 + i;
            float o = 0.f;
            #pragma unroll
            for (int k = 0; k < kK; ++k) {
                const float w = (t == 0) ? 1.0f : ap[k] * oma[k];
                S[k] = fmaf(xv, w, S[k]);
                o = fmaf(S[k] * mixw[k], fminf(vi[k], 1e8f), o);
                ap[k] *= a[k];
                vi[k] *= inva[k];
            }
            op[(size_t)i * kC] = o;
        }
    }
}

extern "C" void kernel_launch(void* const* d_in, const int* in_sizes, int n_in,
                              void* d_out, int out_size, void* d_ws, size_t ws_size,
                              hipStream_t stream) {
    const float* x  = (const float*)d_in[0];
    const float* la = (const float*)d_in[1];
    const float* ml = (const float*)d_in[2];
    float* o = (float*)d_out;

    const int blocks = kB * (kC / kCTile);  // 256 * 8 = 2048 blocks, 256 thr
    ema_mix_kernel<<<dim3(blocks), dim3(256), 0, stream>>>(x, la, ml, o);
}

// Round 3
// 73.180 us; speedup vs baseline: 1.2790x; 1.2790x over previous
//
#include <hip/hip_runtime.h>

namespace {
constexpr int kB = 256;
constexpr int kT = 336;
constexpr int kC = 512;
constexpr int kK = 3;
constexpr int kU = 16;   // 336 = 21 * 16
}

// One thread per (b, c): single pass over T (minimum HBM traffic: x once in,
// out once). Per-wave MLP is the lever: 16 x-loads staged in registers while
// the previous 16 are consumed. __launch_bounds__(256, 2) caps at 2 waves/EU
// (grid is 2 waves/SIMD anyway) so the allocator has ~256 VGPRs and the
// staging buffer actually lives in registers (r2's VGPR=32/36 proved the
// compiler collapsed it when squeezed).
__global__ __launch_bounds__(256, 2) void ema_mix_kernel(
    const float* __restrict__ x,
    const float* __restrict__ logit_alpha,
    const float* __restrict__ mix_logits,
    float* __restrict__ out)
{
    const int c = ((blockIdx.x & 1) << 8) | threadIdx.x;
    const int b = blockIdx.x >> 1;

    // ---- per-(k,c) parameters (once per thread) ----
    float a[kK], oma[kK], inva[kK], mixw[kK];
    {
        float logits[kK];
        float lmax = -3.402823e38f;
        #pragma unroll
        for (int k = 0; k < kK; ++k) {
            logits[k] = mix_logits[c * kK + k];
            lmax = fmaxf(lmax, logits[k]);
        }
        float esum = 0.f;
        #pragma unroll
        for (int k = 0; k < kK; ++k) {
            logits[k] = expf(logits[k] - lmax);
            esum += logits[k];
        }
        const float rs = 1.0f / esum;
        #pragma unroll
        for (int k = 0; k < kK; ++k) {
            mixw[k] = logits[k] * rs;
            const float z = logit_alpha[k * kC + c];
            float s;
            if (z >= 0.f) {
                s = 1.0f / (1.0f + expf(-z));
            } else {
                const float e = expf(z);
                s = e / (1.0f + e);
            }
            s = fminf(fmaxf(s, 1e-4f), (float)(1.0 - 1e-4));
            a[k]    = s;
            oma[k]  = 1.0f - s;
            inva[k] = 1.0f / s;
        }
    }

    const float* xp = x   + (size_t)b * (kT * kC) + c;
    float*       op = out + (size_t)b * (kT * kC) + c;

    float apow[kK], vinv[kK], S[kK];
    #pragma unroll
    for (int k = 0; k < kK; ++k) { apow[k] = 1.f; vinv[k] = 1.f; S[k] = 0.f; }

    // prologue: stage first chunk (16 independent loads in flight)
    float xc[kU], xn[kU];
    #pragma unroll
    for (int i = 0; i < kU; ++i) xc[i] = xp[i * kC];

    for (int tc = 0; tc < kT; tc += kU) {
        const bool more = (tc + kU < kT);
        if (more) {
            // issue next chunk's 16 loads BEFORE touching xc: these have no
            // dependence on the scan chain and should stay in flight under
            // the ~400 cy of compute below.
            #pragma unroll
            for (int i = 0; i < kU; ++i) xn[i] = xp[(tc + kU + i) * kC];
        }
        #pragma unroll
        for (int i = 0; i < kU; ++i) {
            const int t = tc + i;
            const float xv = xc[i];
            float o = 0.f;
            #pragma unroll
            for (int k = 0; k < kK; ++k) {
                const float w = (t == 0) ? 1.0f : apow[k] * oma[k];
                S[k] = fmaf(xv, w, S[k]);
                o = fmaf(S[k] * mixw[k], fminf(vinv[k], 1e8f), o);
                apow[k] *= a[k];
                vinv[k] *= inva[k];
            }
            op[t * kC] = o;
        }
        if (more) {
            #pragma unroll
            for (int i = 0; i < kU; ++i) xc[i] = xn[i];
        }
    }
}

extern "C" void kernel_launch(void* const* d_in, const int* in_sizes, int n_in,
                              void* d_out, int out_size, void* d_ws, size_t ws_size,
                              hipStream_t stream) {
    const float* x  = (const float*)d_in[0];
    const float* la = (const float*)d_in[1];
    const float* ml = (const float*)d_in[2];
    float* o = (float*)d_out;

    const int blocks = kB * (kC / 256);  // 512 blocks x 256 threads = one thread per (b,c)
    ema_mix_kernel<<<dim3(blocks), dim3(256), 0, stream>>>(x, la, ml, o);
}